// Round 13
// baseline (279.169 us; speedup 1.0000x reference)
//
#include <hip/hip_runtime.h>
#include <hip/hip_bf16.h>
#include <cstddef>
#include <cstdint>

typedef _Float16 half_t;
typedef _Float16 half8  __attribute__((ext_vector_type(8)));
typedef _Float16 half4v __attribute__((ext_vector_type(4)));
typedef float    f32x4  __attribute__((ext_vector_type(4)));

#define SCALE 0.17677669529663687f   // 1/sqrt(32)

// workspace layout (bytes):
//   [0,        221184)   wqfrag  fragment-major qkv weights fp16 (K1 input)
//                        -- after K1 runs, the first 196608 B are overwritten
//                           by mb16[4][6][64][64] fp16 masked-bias table (K2)
//   [221184,   294912)   wofrag  fragment-major out-proj weights fp16
//   [294912,  38830080)  q_ws    [2048][6][49][32] fp16
//   [38830080,77365248)  k_ws    [2048][6][49][32] fp16
//   [77365248,118259712) vt_ws   [2048][6][32][52] fp16

// ---------------------------------------------------------------------------
__global__ __launch_bounds__(256) void convert_w(
    const float* __restrict__ w_qkv, const float* __restrict__ w_out,
    half_t* __restrict__ wq, half_t* __restrict__ wo)
{
    int i = blockIdx.x * 256 + threadIdx.x;
    if (i < 110592) {
        int u8 = i >> 3, e = i & 7;
        int c  = u8 & 15;
        int g  = (u8 >> 4) & 3;
        int ks = (u8 >> 6) % 6;
        int ct = u8 / 384;
        wq[i] = (half_t)w_qkv[(16 * ct + c) * 192 + ks * 32 + g * 8 + e];
    } else {
        int j = i - 110592;
        if (j < 36864) {
            int u8 = j >> 3, e = j & 7;
            int c  = u8 & 15;
            int g  = (u8 >> 4) & 3;
            int ks = (u8 >> 6) % 6;
            int q  = u8 / 384;
            wo[j] = (half_t)w_out[(16 * q + c) * 192 + ks * 32 + g * 8 + e];
        }
    }
}

// ---------------------------------------------------------------------------
// Masked relative-position bias table: mb[4][6][64][64] fp16.
// Mask class mc = 2*(nh==7) + (nw==7). Masked / padded entries = -60000.
// ---------------------------------------------------------------------------
__global__ __launch_bounds__(256) void build_bias(
    const float* __restrict__ pos_enc, half_t* __restrict__ mb)
{
    int idx = blockIdx.x * 256 + threadIdx.x;   // < 98304
    int j   = idx & 63;
    int i   = (idx >> 6) & 63;
    int hmc = idx >> 12;
    int h   = hmc % 6, mc = hmc / 6;
    float v = -60000.f;
    if (i < 49 && j < 49) {
        int yi = i / 7, xi = i - 7 * yi;
        int yj = j / 7, xj = j - 7 * yj;
        int ri = ((mc & 2) ? (yi < 4 ? 1 : 2) : 0) * 3 + ((mc & 1) ? (xi < 4 ? 1 : 2) : 0);
        int rj = ((mc & 2) ? (yj < 4 ? 1 : 2) : 0) * 3 + ((mc & 1) ? (xj < 4 ? 1 : 2) : 0);
        if (ri == rj) v = pos_enc[h * 169 + (yi - yj + 6) * 13 + (xi - xj + 6)];
    }
    mb[idx] = (half_t)v;
}

// ---------------------------------------------------------------------------
// K1: QKV projection. grid (2048, 3) x 128 threads; block = (window, kind).
// ZERO LDS, ZERO barriers; fragment-major weight B-frags stream from L2.
// Kind-split triples resident blocks/CU (TLP) vs round-12's 2048-block grid.
// Wave mh handles tokens 32mh..32mh+31 (2 M-tiles), this kind's 12 col-tiles.
// ---------------------------------------------------------------------------
__global__ __launch_bounds__(128, 8) void swin_qkv(
    const float*  __restrict__ x,
    const half_t* __restrict__ wqfrag,
    const float*  __restrict__ b_qkv,
    half_t* __restrict__ qws,
    half_t* __restrict__ kws,
    half_t* __restrict__ vtws)
{
    const int tid  = threadIdx.x;
    const int mh   = tid >> 6, lane = tid & 63;
    const int c    = lane & 15, g = lane >> 4;
    const int w    = blockIdx.x;
    const int kind = blockIdx.y;     // 0=q, 1=k, 2=v (wave-uniform)
    const int b    = w >> 6, win = w & 63, nh = win >> 3, nw = win & 7;
    const int wh0  = w * 6;

    // ---- shifted-window gather of 32 tokens into A-fragments -------------
    half8 xf[2][6];
    #pragma unroll
    for (int t = 0; t < 2; ++t) {
        int tok = 32 * mh + 16 * t + c;
        if (tok < 49) {
            int ty = tok / 7, tx = tok - ty * 7;
            int sy = nh * 7 + ty + 3; if (sy >= 56) sy -= 56;
            int sx = nw * 7 + tx + 3; if (sx >= 56) sx -= 56;
            const float* xr = x + ((size_t)b * 3136 + sy * 56 + sx) * 192 + g * 8;
            #pragma unroll
            for (int ks = 0; ks < 6; ++ks) {
                float4 v0 = *(const float4*)(xr + ks * 32);
                float4 v1 = *(const float4*)(xr + ks * 32 + 4);
                xf[t][ks] = (half8){(half_t)v0.x, (half_t)v0.y, (half_t)v0.z, (half_t)v0.w,
                                    (half_t)v1.x, (half_t)v1.y, (half_t)v1.z, (half_t)v1.w};
            }
        } else {
            #pragma unroll
            for (int ks = 0; ks < 6; ++ks)
                xf[t][ks] = (half8){(half_t)0.f, (half_t)0.f, (half_t)0.f, (half_t)0.f,
                                    (half_t)0.f, (half_t)0.f, (half_t)0.f, (half_t)0.f};
        }
    }

    half_t* const qk_dst = (kind == 0) ? qws : kws;

    #pragma unroll 4
    for (int q12 = 0; q12 < 12; ++q12) {
        const int ct  = kind * 12 + q12;
        const half_t* wp = wqfrag + ((size_t)ct * 384 + lane) * 8;
        half8 bf[6];
        #pragma unroll
        for (int ks = 0; ks < 6; ++ks) bf[ks] = *(const half8*)(wp + ks * 512);
        f32x4 a0 = (f32x4){0.f, 0.f, 0.f, 0.f};
        f32x4 a1 = (f32x4){0.f, 0.f, 0.f, 0.f};
        #pragma unroll
        for (int ks = 0; ks < 6; ++ks) {
            a0 = __builtin_amdgcn_mfma_f32_16x16x32_f16(xf[0][ks], bf[ks], a0, 0, 0, 0);
            a1 = __builtin_amdgcn_mfma_f32_16x16x32_f16(xf[1][ks], bf[ks], a1, 0, 0, 0);
        }
        const int h = q12 >> 1, d = ((q12 & 1) << 4) + c;
        const float bias = b_qkv[16 * ct + c];
        const int wh = wh0 + h;
        if (kind == 2) {
            #pragma unroll
            for (int t = 0; t < 2; ++t) {
                f32x4 a = t ? a1 : a0;
                int tok0 = 32 * mh + 16 * t + 4 * g;
                if (tok0 <= 48) {
                    half4v pv = (half4v){(half_t)(a[0] + bias), (half_t)(a[1] + bias),
                                         (half_t)(a[2] + bias), (half_t)(a[3] + bias)};
                    *(half4v*)(vtws + (size_t)(wh * 32 + d) * 52 + tok0) = pv;
                }
            }
        } else {
            #pragma unroll
            for (int t = 0; t < 2; ++t) {
                f32x4 a = t ? a1 : a0;
                #pragma unroll
                for (int r = 0; r < 4; ++r) {
                    int tok = 32 * mh + 16 * t + 4 * g + r;
                    if (tok < 49)
                        qk_dst[((size_t)wh * 49 + tok) * 32 + d] = (half_t)(a[r] + bias);
                }
            }
        }
    }
}

// ---------------------------------------------------------------------------
// K2: attention (3 heads/wave; K staged in LDS; q/bias/V prefetched one head
// ahead in statically-indexed register buffers) + out-projection through a
// conflict-free frag-major LDS O-buffer + un-shift scatter.
// grid = 2048, 512 threads = 8 waves; wave (ti, hf): heads h = 3*hf + p.
// (byte-identical to round 8)
// ---------------------------------------------------------------------------
__global__ __launch_bounds__(512, 4) void swin_attn_proj(
    const half_t* __restrict__ qws,
    const half_t* __restrict__ kws,
    const half_t* __restrict__ vtws,
    const half_t* __restrict__ mb16,
    const half_t* __restrict__ wofrag,
    const float*  __restrict__ b_out,
    float* __restrict__ out)
{
    __shared__ __align__(16) half_t sK[1536 * 8];        // 24576 B (18816 used)
    __shared__ __align__(16) half_t sAf[6 * 4 * 64 * 8]; // 24576 B frag-major O

    const int w    = blockIdx.x;
    const int b    = w >> 6, win = w & 63, nh = win >> 3, nw = win & 7;
    const int tid  = threadIdx.x;
    const int wave = tid >> 6, lane = tid & 63;
    const int c    = lane & 15, g = lane >> 4;
    const int ti   = wave & 3, hf = wave >> 2;
    const int i_tok = 16 * ti + c;
    const int mc   = 2 * (nh == 7) + (nw == 7);

    // ---- stage this window's K (6 heads x 49x32 fp16) into LDS linearly --
    {
        const half_t* src = kws + (size_t)w * 9408;
        #pragma unroll
        for (int rnd = 0; rnd < 3; ++rnd) {
            int u = tid + rnd * 512;   // up to 1536 units (tail overread is benign)
            __builtin_amdgcn_global_load_lds(
                (const __attribute__((address_space(1))) unsigned int*)(src + u * 8),
                (__attribute__((address_space(3))) unsigned int*)(&sK[u * 8]), 16, 0, 0);
        }
    }

    half8  qA, qB;
    half4v bA[4], bB[4];
    half4v vA[8], vB[8];

#define LOADH(QF, BF, VF, hh) do {                                              \
        const int wh_ = w * 6 + (hh);                                           \
        QF = *(const half8*)(qws + ((size_t)wh_ * 49 + i_tok) * 32 + g * 8);    \
        const half_t* mrow_ = mb16 + ((size_t)(mc * 6 + (hh)) * 64 + i_tok) * 64; \
        _Pragma("unroll")                                                       \
        for (int tj_ = 0; tj_ < 4; ++tj_)                                       \
            BF[tj_] = *(const half4v*)(mrow_ + 16 * tj_ + 4 * g);               \
        const half_t* vh_ = vtws + (size_t)wh_ * 1664;                          \
        _Pragma("unroll")                                                       \
        for (int tj_ = 0; tj_ < 4; ++tj_) {                                     \
            VF[2 * tj_]     = *(const half4v*)(vh_ + c * 52 + 16 * tj_ + 4 * g);        \
            VF[2 * tj_ + 1] = *(const half4v*)(vh_ + (16 + c) * 52 + 16 * tj_ + 4 * g); \
        }                                                                       \
    } while (0)

    // prefetch head 0 while staging is in flight
    LOADH(qA, bA, vA, 3 * hf);
    __syncthreads();   // staging (and prefetch) complete

    #pragma unroll
    for (int p = 0; p < 3; ++p) {
        const int h = 3 * hf + p;
        // prefetch next head into the other buffer set
        if (p == 0) LOADH(qB, bB, vB, h + 1);
        if (p == 1) LOADH(qA, bA, vA, h + 1);

        const half8&  qf = (p == 1) ? qB : qA;
        const half4v* bf = (p == 1) ? bB : bA;
        const half4v* vf = (p == 1) ? vB : vA;

        // K fragments from LDS (stride-64B rows: wire-speed ds_read_b128)
        half8 kf[4];
        #pragma unroll
        for (int tj = 0; tj < 4; ++tj)
            kf[tj] = *(const half8*)&sK[((size_t)h * 49 + 16 * tj + c) * 32 + g * 8];

        // S^T = K * Q^T ; lane holds S[i_tok][j = 16tj + 4g + r]
        f32x4 st[4];
        #pragma unroll
        for (int tj = 0; tj < 4; ++tj) {
            f32x4 z = (f32x4){0.f, 0.f, 0.f, 0.f};
            st[tj] = __builtin_amdgcn_mfma_f32_16x16x32_f16(kf[tj], qf, z, 0, 0, 0);
        }
        #pragma unroll
        for (int tj = 0; tj < 4; ++tj)
            #pragma unroll
            for (int r = 0; r < 4; ++r)
                st[tj][r] = st[tj][r] * SCALE + (float)bf[tj][r];

        // softmax (16 in-register + lane-pairs 16, 32 apart)
        float m = st[0][0];
        #pragma unroll
        for (int tj = 0; tj < 4; ++tj)
            #pragma unroll
            for (int r = 0; r < 4; ++r) m = fmaxf(m, st[tj][r]);
        m = fmaxf(m, __shfl_xor(m, 16));
        m = fmaxf(m, __shfl_xor(m, 32));
        float sum = 0.f;
        #pragma unroll
        for (int tj = 0; tj < 4; ++tj)
            #pragma unroll
            for (int r = 0; r < 4; ++r) {
                float e = __expf(st[tj][r] - m);
                st[tj][r] = e;
                sum += e;
            }
        sum += __shfl_xor(sum, 16);
        sum += __shfl_xor(sum, 32);
        float inv = 1.0f / sum;
        half4v pa[4];
        #pragma unroll
        for (int tj = 0; tj < 4; ++tj)
            pa[tj] = (half4v){(half_t)(st[tj][0] * inv), (half_t)(st[tj][1] * inv),
                              (half_t)(st[tj][2] * inv), (half_t)(st[tj][3] * inv)};

        // PV: O^T = V^T * P^T
        f32x4 o0 = (f32x4){0.f, 0.f, 0.f, 0.f};
        f32x4 o1 = (f32x4){0.f, 0.f, 0.f, 0.f};
        #pragma unroll
        for (int tj = 0; tj < 4; ++tj) {
            o0 = __builtin_amdgcn_mfma_f32_16x16x16f16(vf[2 * tj],     pa[tj], o0, 0, 0, 0);
            o1 = __builtin_amdgcn_mfma_f32_16x16x16f16(vf[2 * tj + 1], pa[tj], o1, 0, 0, 0);
        }
        // frag-major O store
        {
            int base = (((h * 4 + ti) * 64 + (g >> 1) * 16 + c) << 3) + (g & 1) * 4;
            *(half4v*)&sAf[base] =
                (half4v){(half_t)o0[0], (half_t)o0[1], (half_t)o0[2], (half_t)o0[3]};
            *(half4v*)&sAf[base + 256] =
                (half4v){(half_t)o1[0], (half_t)o1[1], (half_t)o1[2], (half_t)o1[3]};
        }
    }
#undef LOADH
    __syncthreads();

    // ---- out-projection + un-shift scatter -------------------------------
    {
        f32x4 pacc[6];
        float bo[6];
        #pragma unroll
        for (int q = 0; q < 6; ++q) {
            pacc[q] = (f32x4){0.f, 0.f, 0.f, 0.f};
            bo[q] = b_out[16 * (6 * hf + q) + c];
        }
        #pragma unroll
        for (int ks = 0; ks < 6; ++ks) {
            half8 aF = *(const half8*)&sAf[((ks * 4 + ti) * 64 + lane) * 8];
            #pragma unroll
            for (int q = 0; q < 6; ++q) {
                int ct = 6 * hf + q;
                half8 bF = *(const half8*)(wofrag + ((size_t)(ct * 6 + ks) * 64 + lane) * 8);
                pacc[q] = __builtin_amdgcn_mfma_f32_16x16x32_f16(aF, bF, pacc[q], 0, 0, 0);
            }
        }
        #pragma unroll
        for (int r = 0; r < 4; ++r) {
            int tok = 16 * ti + g * 4 + r;
            if (tok < 49) {
                int ty = tok / 7, tx = tok - ty * 7;
                int dy = nh * 7 + ty + 3; if (dy >= 56) dy -= 56;
                int dx = nw * 7 + tx + 3; if (dx >= 56) dx -= 56;
                float* op = out + ((size_t)b * 3136 + dy * 56 + dx) * 192;
                #pragma unroll
                for (int q = 0; q < 6; ++q)
                    op[16 * (6 * hf + q) + c] = pacc[q][r] + bo[q];
            }
        }
    }
}

// ---------------------------------------------------------------------------
extern "C" void kernel_launch(void* const* d_in, const int* in_sizes, int n_in,
                              void* d_out, int out_size, void* d_ws, size_t ws_size,
                              hipStream_t stream) {
    const float* x       = (const float*)d_in[0];
    const float* w_qkv   = (const float*)d_in[1];
    const float* b_qkv   = (const float*)d_in[2];
    const float* w_out   = (const float*)d_in[3];
    const float* b_out   = (const float*)d_in[4];
    const float* pos_enc = (const float*)d_in[5];
    float* out = (float*)d_out;

    half_t* wqf  = (half_t*)d_ws;                       // K1 weights (then mb16)
    half_t* mb16 = (half_t*)d_ws;                       // bias table (after K1)
    half_t* wof  = (half_t*)((char*)d_ws + 221184);
    half_t* qws  = (half_t*)((char*)d_ws + 294912);
    half_t* kws  = (half_t*)((char*)d_ws + 38830080);
    half_t* vtws = (half_t*)((char*)d_ws + 77365248);

    convert_w<<<dim3(576), dim3(256), 0, stream>>>(w_qkv, w_out, wqf, wof);
    swin_qkv<<<dim3(2048, 3), dim3(128), 0, stream>>>(x, wqf, b_qkv, qws, kws, vtws);
    build_bias<<<dim3(384), dim3(256), 0, stream>>>(pos_enc, mb16);
    swin_attn_proj<<<dim3(2048), dim3(512), 0, stream>>>(
        qws, kws, vtws, mb16, wof, b_out, out);
}

// Round 14
// 131.792 us; speedup vs baseline: 2.1182x; 2.1182x over previous
//
#include <hip/hip_runtime.h>
#include <hip/hip_bf16.h>
#include <cstddef>
#include <cstdint>

typedef _Float16 half_t;
typedef _Float16 half8  __attribute__((ext_vector_type(8)));
typedef _Float16 half4v __attribute__((ext_vector_type(4)));
typedef float    f32x4  __attribute__((ext_vector_type(4)));

#define SCALE 0.17677669529663687f   // 1/sqrt(32)

// workspace layout (bytes):
//   [0,        221184)   wqfrag  fragment-major qkv weights fp16 (K1 input)
//                        -- after K1, first 196608 B overwritten by mb16
//   [221184,   294912)   wofrag  fragment-major out-proj weights fp16
//   [294912,   38043648) q_raw   [wh=12288][dh=2][tm=3][lane=64][4] fp16 (q^T frags)
//   [38043648, 75792384) k_raw   same layout (k^T frags)
//   [75792384, 113541120) v_raw  same layout (V frags, tok-major rows)
//   [113541120,114327552) tinyQ  [wh][dh][16] fp16  (token-48 sliver)
//   [114327552,115113984) tinyK  [wh][dh][16] fp16
//   [115113984,115900416) tinyV  [wh][dt][16] fp16
// total 115.9 MB (< proven 118.26 MB)

// ---------------------------------------------------------------------------
__global__ __launch_bounds__(256) void convert_w(
    const float* __restrict__ w_qkv, const float* __restrict__ w_out,
    half_t* __restrict__ wq, half_t* __restrict__ wo)
{
    int i = blockIdx.x * 256 + threadIdx.x;
    if (i < 110592) {
        int u8 = i >> 3, e = i & 7;
        int c  = u8 & 15;
        int g  = (u8 >> 4) & 3;
        int ks = (u8 >> 6) % 6;
        int ct = u8 / 384;
        wq[i] = (half_t)w_qkv[(16 * ct + c) * 192 + ks * 32 + g * 8 + e];
    } else {
        int j = i - 110592;
        if (j < 36864) {
            int u8 = j >> 3, e = j & 7;
            int c  = u8 & 15;
            int g  = (u8 >> 4) & 3;
            int ks = (u8 >> 6) % 6;
            int q  = u8 / 384;
            wo[j] = (half_t)w_out[(16 * q + c) * 192 + ks * 32 + g * 8 + e];
        }
    }
}

// ---------------------------------------------------------------------------
// Masked relative-position bias table: mb[4][6][64][64] fp16.
// Mask class mc = 2*(nh==7) + (nw==7). Masked / padded entries = -60000.
// ---------------------------------------------------------------------------
__global__ __launch_bounds__(256) void build_bias(
    const float* __restrict__ pos_enc, half_t* __restrict__ mb)
{
    int idx = blockIdx.x * 256 + threadIdx.x;   // < 98304
    int j   = idx & 63;
    int i   = (idx >> 6) & 63;
    int hmc = idx >> 12;
    int h   = hmc % 6, mc = hmc / 6;
    float v = -60000.f;
    if (i < 49 && j < 49) {
        int yi = i / 7, xi = i - 7 * yi;
        int yj = j / 7, xj = j - 7 * yj;
        int ri = ((mc & 2) ? (yi < 4 ? 1 : 2) : 0) * 3 + ((mc & 1) ? (xi < 4 ? 1 : 2) : 0);
        int rj = ((mc & 2) ? (yj < 4 ? 1 : 2) : 0) * 3 + ((mc & 1) ? (xj < 4 ? 1 : 2) : 0);
        if (ri == rj) v = pos_enc[h * 169 + (yi - yj + 6) * 13 + (xi - xj + 6)];
    }
    mb[idx] = (half_t)v;
}

// ---------------------------------------------------------------------------
// K1: QKV projection. 2048 blocks x 128 threads; block = 1 window, 2 waves.
// Zero LDS / zero barriers. q,k computed with SWAPPED operands -> C-tile is
// q^T/k^T whose per-lane half4v is directly K2's MFMA fragment; all stores
// are wave-contiguous half4v (72/wave vs 216 scalar before).
// Tile tm=3 (tokens 48..63; only 48 real) compressed into tiny buffers.
// ---------------------------------------------------------------------------
__global__ __launch_bounds__(128, 4) void swin_qkv(
    const float*  __restrict__ x,
    const half_t* __restrict__ wqfrag,
    const float*  __restrict__ b_qkv,
    half_t* __restrict__ qraw,
    half_t* __restrict__ kraw,
    half_t* __restrict__ vraw,
    half_t* __restrict__ tinyQ,
    half_t* __restrict__ tinyK,
    half_t* __restrict__ tinyV)
{
    const int tid  = threadIdx.x;
    const int mh   = tid >> 6, lane = tid & 63;
    const int c    = lane & 15, g = lane >> 4;
    const int w    = blockIdx.x;
    const int b    = w >> 6, win = w & 63, nh = win >> 3, nw = win & 7;
    const int wh0  = w * 6;

    // ---- shifted-window gather of 32 tokens into A/B fragments -----------
    half8 xf[2][6];
    #pragma unroll
    for (int t = 0; t < 2; ++t) {
        int tok = 32 * mh + 16 * t + c;
        if (tok < 49) {
            int ty = tok / 7, tx = tok - ty * 7;
            int sy = nh * 7 + ty + 3; if (sy >= 56) sy -= 56;
            int sx = nw * 7 + tx + 3; if (sx >= 56) sx -= 56;
            const float* xr = x + ((size_t)b * 3136 + sy * 56 + sx) * 192 + g * 8;
            #pragma unroll
            for (int ks = 0; ks < 6; ++ks) {
                float4 v0 = *(const float4*)(xr + ks * 32);
                float4 v1 = *(const float4*)(xr + ks * 32 + 4);
                xf[t][ks] = (half8){(half_t)v0.x, (half_t)v0.y, (half_t)v0.z, (half_t)v0.w,
                                    (half_t)v1.x, (half_t)v1.y, (half_t)v1.z, (half_t)v1.w};
            }
        } else {
            #pragma unroll
            for (int ks = 0; ks < 6; ++ks)
                xf[t][ks] = (half8){(half_t)0.f, (half_t)0.f, (half_t)0.f, (half_t)0.f,
                                    (half_t)0.f, (half_t)0.f, (half_t)0.f, (half_t)0.f};
        }
    }

    // ---- q,k: swapped operands -> C = [d-rows][tok-cols] ------------------
    #pragma unroll 4
    for (int ct = 0; ct < 24; ++ct) {
        const half_t* wp = wqfrag + ((size_t)ct * 384 + lane) * 8;
        half8 bfm[6];
        #pragma unroll
        for (int ks = 0; ks < 6; ++ks) bfm[ks] = *(const half8*)(wp + ks * 512);
        f32x4 a0 = (f32x4){0.f, 0.f, 0.f, 0.f};
        f32x4 a1 = (f32x4){0.f, 0.f, 0.f, 0.f};
        #pragma unroll
        for (int ks = 0; ks < 6; ++ks) {
            a0 = __builtin_amdgcn_mfma_f32_16x16x32_f16(bfm[ks], xf[0][ks], a0, 0, 0, 0);
            a1 = __builtin_amdgcn_mfma_f32_16x16x32_f16(bfm[ks], xf[1][ks], a1, 0, 0, 0);
        }
        const int kind = ct / 12, rem = ct - 12 * kind;   // 0=q, 1=k
        const int h = rem >> 1, dh = rem & 1;
        float4 bq = *(const float4*)(b_qkv + 16 * ct + 4 * g);  // bias[4g+r]
        half_t* dst = kind ? kraw : qraw;
        half_t* tny = kind ? tinyK : tinyQ;
        const size_t base = ((size_t)(wh0 + h) * 2 + dh) * 3;
        #pragma unroll
        for (int t = 0; t < 2; ++t) {
            f32x4 a = t ? a1 : a0;
            int tm = 2 * mh + t;
            half4v pv = (half4v){(half_t)(a[0] + bq.x), (half_t)(a[1] + bq.y),
                                 (half_t)(a[2] + bq.z), (half_t)(a[3] + bq.w)};
            if (tm < 3) {
                *(half4v*)(dst + ((base + tm) * 64 + lane) * 4) = pv;
            } else if (c == 0) {
                *(half4v*)(tny + ((wh0 + h) * 2 + dh) * 16 + 4 * g) = pv;
            }
        }
    }

    // ---- v: normal operands -> C = [tok-rows][d-cols] ---------------------
    #pragma unroll 4
    for (int ct = 24; ct < 36; ++ct) {
        const half_t* wp = wqfrag + ((size_t)ct * 384 + lane) * 8;
        half8 bfm[6];
        #pragma unroll
        for (int ks = 0; ks < 6; ++ks) bfm[ks] = *(const half8*)(wp + ks * 512);
        f32x4 a0 = (f32x4){0.f, 0.f, 0.f, 0.f};
        f32x4 a1 = (f32x4){0.f, 0.f, 0.f, 0.f};
        #pragma unroll
        for (int ks = 0; ks < 6; ++ks) {
            a0 = __builtin_amdgcn_mfma_f32_16x16x32_f16(xf[0][ks], bfm[ks], a0, 0, 0, 0);
            a1 = __builtin_amdgcn_mfma_f32_16x16x32_f16(xf[1][ks], bfm[ks], a1, 0, 0, 0);
        }
        const int rem = ct - 24;
        const int h = rem >> 1, dh = rem & 1;
        const float bv = b_qkv[16 * ct + c];
        const size_t base = ((size_t)(wh0 + h) * 2 + dh) * 3;
        #pragma unroll
        for (int t = 0; t < 2; ++t) {
            f32x4 a = t ? a1 : a0;
            int tm = 2 * mh + t;
            if (tm < 3) {
                half4v pv = (half4v){(half_t)(a[0] + bv), (half_t)(a[1] + bv),
                                     (half_t)(a[2] + bv), (half_t)(a[3] + bv)};
                *(half4v*)(vraw + ((base + tm) * 64 + lane) * 4) = pv;
            } else if (g == 0) {
                tinyV[((wh0 + h) * 2 + dh) * 16 + c] = (half_t)(a[0] + bv);   // V[48][16dh+c]
            }
        }
    }
}

// ---------------------------------------------------------------------------
// K2: attention (3 heads/wave; k_raw staged in LDS; q/bias/V/tiny prefetched
// one head ahead) + out-projection (frag-major sAf) + un-shift scatter.
// grid = 2048, 512 threads = 8 waves; wave (ti, hf): heads h = 3*hf + p.
// All fragment loads are contiguous half4v (raw layouts from K1).
// ---------------------------------------------------------------------------
__global__ __launch_bounds__(512, 4) void swin_attn_proj(
    const half_t* __restrict__ qraw,
    const half_t* __restrict__ kraw,
    const half_t* __restrict__ vraw,
    const half_t* __restrict__ tinyQ,
    const half_t* __restrict__ tinyK,
    const half_t* __restrict__ tinyV,
    const half_t* __restrict__ mb16,
    const half_t* __restrict__ wofrag,
    const float*  __restrict__ b_out,
    float* __restrict__ out)
{
    __shared__ __align__(16) half_t sK[1536 * 8];        // 24576 B (18432 used)
    __shared__ __align__(16) half_t sAf[6 * 4 * 64 * 8]; // 24576 B frag-major O

    const int w    = blockIdx.x;
    const int b    = w >> 6, win = w & 63, nh = win >> 3, nw = win & 7;
    const int tid  = threadIdx.x;
    const int wave = tid >> 6, lane = tid & 63;
    const int c    = lane & 15, g = lane >> 4;
    const int ti   = wave & 3, hf = wave >> 2;
    const int i_tok = 16 * ti + c;
    const int mc   = 2 * (nh == 7) + (nw == 7);

    // ---- stage this window's k_raw block (6 heads x 3072 B) into LDS -----
    {
        const half_t* src = kraw + (size_t)w * 9216;
        #pragma unroll
        for (int rnd = 0; rnd < 3; ++rnd) {
            int u = tid + rnd * 512;   // 1536 issues; tail overread benign
            __builtin_amdgcn_global_load_lds(
                (const __attribute__((address_space(1))) unsigned int*)(src + u * 8),
                (__attribute__((address_space(3))) unsigned int*)(&sK[u * 8]), 16, 0, 0);
        }
    }

    half4v qA[2], qB[2];
    half4v bA[4], bB[4];
    half4v vA[6], vB[6];
    half4v v3A[2], v3B[2];
    half4v k3A[2], k3B[2];

#define LOADH(QF, BF, VF, V3, K3, hh) do {                                        \
        const int wh_ = w * 6 + (hh);                                             \
        if (ti < 3) {                                                             \
            QF[0] = *(const half4v*)(qraw + (((size_t)wh_ * 2 + 0) * 3 + ti) * 256 + lane * 4); \
            QF[1] = *(const half4v*)(qraw + (((size_t)wh_ * 2 + 1) * 3 + ti) * 256 + lane * 4); \
        } else {                                                                  \
            QF[0] = *(const half4v*)(tinyQ + (wh_ * 2 + 0) * 16 + 4 * g);         \
            QF[1] = *(const half4v*)(tinyQ + (wh_ * 2 + 1) * 16 + 4 * g);         \
        }                                                                         \
        const half_t* mrow_ = mb16 + ((size_t)(mc * 6 + (hh)) * 64 + i_tok) * 64; \
        _Pragma("unroll")                                                         \
        for (int tj_ = 0; tj_ < 4; ++tj_)                                         \
            BF[tj_] = *(const half4v*)(mrow_ + 16 * tj_ + 4 * g);                 \
        _Pragma("unroll")                                                         \
        for (int tj_ = 0; tj_ < 3; ++tj_) {                                       \
            VF[2 * tj_]     = *(const half4v*)(vraw + (((size_t)wh_ * 2 + 0) * 3 + tj_) * 256 + lane * 4); \
            VF[2 * tj_ + 1] = *(const half4v*)(vraw + (((size_t)wh_ * 2 + 1) * 3 + tj_) * 256 + lane * 4); \
        }                                                                         \
        {                                                                         \
            half_t tv0 = tinyV[(wh_ * 2 + 0) * 16 + c];                           \
            half_t tv1 = tinyV[(wh_ * 2 + 1) * 16 + c];                           \
            V3[0] = (half4v){tv0, tv0, tv0, tv0};                                 \
            V3[1] = (half4v){tv1, tv1, tv1, tv1};                                 \
        }                                                                         \
        K3[0] = *(const half4v*)(tinyK + (wh_ * 2 + 0) * 16 + 4 * g);             \
        K3[1] = *(const half4v*)(tinyK + (wh_ * 2 + 1) * 16 + 4 * g);             \
    } while (0)

    // prefetch head 0 while staging is in flight
    LOADH(qA, bA, vA, v3A, k3A, 3 * hf);
    __syncthreads();   // staging (and prefetch) complete

    #pragma unroll
    for (int p = 0; p < 3; ++p) {
        const int h = 3 * hf + p;
        if (p == 0) LOADH(qB, bB, vB, v3B, k3B, h + 1);
        if (p == 1) LOADH(qA, bA, vA, v3A, k3A, h + 1);

        const half4v* qf = (p == 1) ? qB : qA;
        const half4v* bf = (p == 1) ? bB : bA;
        const half4v* vf = (p == 1) ? vB : vA;
        const half4v* v3 = (p == 1) ? v3B : v3A;
        const half4v* k3 = (p == 1) ? k3B : k3A;

        // S^T = K * Q^T via 2x k=16 MFMAs per tj (frags straight from raw layouts)
        f32x4 st[4];
        #pragma unroll
        for (int tj = 0; tj < 4; ++tj) {
            half4v ka0, ka1;
            if (tj < 3) {
                ka0 = *(const half4v*)&sK[(size_t)h * 1536 + ((0 * 3 + tj) * 64 + lane) * 4];
                ka1 = *(const half4v*)&sK[(size_t)h * 1536 + ((1 * 3 + tj) * 64 + lane) * 4];
            } else {
                ka0 = k3[0];
                ka1 = k3[1];
            }
            f32x4 z = (f32x4){0.f, 0.f, 0.f, 0.f};
            z = __builtin_amdgcn_mfma_f32_16x16x16f16(ka0, qf[0], z, 0, 0, 0);
            st[tj] = __builtin_amdgcn_mfma_f32_16x16x16f16(ka1, qf[1], z, 0, 0, 0);
        }
        #pragma unroll
        for (int tj = 0; tj < 4; ++tj)
            #pragma unroll
            for (int r = 0; r < 4; ++r)
                st[tj][r] = st[tj][r] * SCALE + (float)bf[tj][r];

        // softmax (16 in-register + lane-pairs 16, 32 apart)
        float m = st[0][0];
        #pragma unroll
        for (int tj = 0; tj < 4; ++tj)
            #pragma unroll
            for (int r = 0; r < 4; ++r) m = fmaxf(m, st[tj][r]);
        m = fmaxf(m, __shfl_xor(m, 16));
        m = fmaxf(m, __shfl_xor(m, 32));
        float sum = 0.f;
        #pragma unroll
        for (int tj = 0; tj < 4; ++tj)
            #pragma unroll
            for (int r = 0; r < 4; ++r) {
                float e = __expf(st[tj][r] - m);
                st[tj][r] = e;
                sum += e;
            }
        sum += __shfl_xor(sum, 16);
        sum += __shfl_xor(sum, 32);
        float inv = 1.0f / sum;
        half4v pa[4];
        #pragma unroll
        for (int tj = 0; tj < 4; ++tj)
            pa[tj] = (half4v){(half_t)(st[tj][0] * inv), (half_t)(st[tj][1] * inv),
                              (half_t)(st[tj][2] * inv), (half_t)(st[tj][3] * inv)};

        // PV: O^T = V^T * P^T
        f32x4 o0 = (f32x4){0.f, 0.f, 0.f, 0.f};
        f32x4 o1 = (f32x4){0.f, 0.f, 0.f, 0.f};
        #pragma unroll
        for (int tj = 0; tj < 3; ++tj) {
            o0 = __builtin_amdgcn_mfma_f32_16x16x16f16(vf[2 * tj],     pa[tj], o0, 0, 0, 0);
            o1 = __builtin_amdgcn_mfma_f32_16x16x16f16(vf[2 * tj + 1], pa[tj], o1, 0, 0, 0);
        }
        o0 = __builtin_amdgcn_mfma_f32_16x16x16f16(v3[0], pa[3], o0, 0, 0, 0);
        o1 = __builtin_amdgcn_mfma_f32_16x16x16f16(v3[1], pa[3], o1, 0, 0, 0);

        // frag-major O store
        {
            int base = (((h * 4 + ti) * 64 + (g >> 1) * 16 + c) << 3) + (g & 1) * 4;
            *(half4v*)&sAf[base] =
                (half4v){(half_t)o0[0], (half_t)o0[1], (half_t)o0[2], (half_t)o0[3]};
            *(half4v*)&sAf[base + 256] =
                (half4v){(half_t)o1[0], (half_t)o1[1], (half_t)o1[2], (half_t)o1[3]};
        }
    }
#undef LOADH
    __syncthreads();

    // ---- out-projection + un-shift scatter -------------------------------
    {
        f32x4 pacc[6];
        float bo[6];
        #pragma unroll
        for (int q = 0; q < 6; ++q) {
            pacc[q] = (f32x4){0.f, 0.f, 0.f, 0.f};
            bo[q] = b_out[16 * (6 * hf + q) + c];
        }
        #pragma unroll
        for (int ks = 0; ks < 6; ++ks) {
            half8 aF = *(const half8*)&sAf[((ks * 4 + ti) * 64 + lane) * 8];
            #pragma unroll
            for (int q = 0; q < 6; ++q) {
                int ct = 6 * hf + q;
                half8 bF = *(const half8*)(wofrag + ((size_t)(ct * 6 + ks) * 64 + lane) * 8);
                pacc[q] = __builtin_amdgcn_mfma_f32_16x16x32_f16(aF, bF, pacc[q], 0, 0, 0);
            }
        }
        #pragma unroll
        for (int r = 0; r < 4; ++r) {
            int tok = 16 * ti + g * 4 + r;
            if (tok < 49) {
                int ty = tok / 7, tx = tok - ty * 7;
                int dy = nh * 7 + ty + 3; if (dy >= 56) dy -= 56;
                int dx = nw * 7 + tx + 3; if (dx >= 56) dx -= 56;
                float* op = out + ((size_t)b * 3136 + dy * 56 + dx) * 192;
                #pragma unroll
                for (int q = 0; q < 6; ++q)
                    op[16 * (6 * hf + q) + c] = pacc[q][r] + bo[q];
            }
        }
    }
}

// ---------------------------------------------------------------------------
extern "C" void kernel_launch(void* const* d_in, const int* in_sizes, int n_in,
                              void* d_out, int out_size, void* d_ws, size_t ws_size,
                              hipStream_t stream) {
    const float* x       = (const float*)d_in[0];
    const float* w_qkv   = (const float*)d_in[1];
    const float* b_qkv   = (const float*)d_in[2];
    const float* w_out   = (const float*)d_in[3];
    const float* b_out   = (const float*)d_in[4];
    const float* pos_enc = (const float*)d_in[5];
    float* out = (float*)d_out;

    half_t* wqf   = (half_t*)d_ws;                          // K1 weights (then mb16)
    half_t* mb16  = (half_t*)d_ws;                          // bias table (after K1)
    half_t* wof   = (half_t*)((char*)d_ws + 221184);
    half_t* qraw  = (half_t*)((char*)d_ws + 294912);
    half_t* kraw  = (half_t*)((char*)d_ws + 38043648);
    half_t* vraw  = (half_t*)((char*)d_ws + 75792384);
    half_t* tinyQ = (half_t*)((char*)d_ws + 113541120);
    half_t* tinyK = (half_t*)((char*)d_ws + 114327552);
    half_t* tinyV = (half_t*)((char*)d_ws + 115113984);

    convert_w<<<dim3(576), dim3(256), 0, stream>>>(w_qkv, w_out, wqf, wof);
    swin_qkv<<<dim3(2048), dim3(128), 0, stream>>>(
        x, wqf, b_qkv, qraw, kraw, vraw, tinyQ, tinyK, tinyV);
    build_bias<<<dim3(384), dim3(256), 0, stream>>>(pos_enc, mb16);
    swin_attn_proj<<<dim3(2048), dim3(512), 0, stream>>>(
        qraw, kraw, vraw, tinyQ, tinyK, tinyV, mb16, wof, b_out, out);
}